// Round 6
// baseline (89.978 us; speedup 1.0000x reference)
//
#include <hip/hip_runtime.h>

// Chamfer loss: B=32, N=M=2048, D=3, fp32 in, scalar fp32 out.
// loss = sum_b [ sum_m min_n d2 + sum_n min_m d2 ] / B
//
// v5: MFMA path. The vector path is issue-limited at ~4 cyc/wave-inst and
// 4 inst/pair (~29 us). Move the dot products to the matrix pipe:
//   s[q][p] = h_p - q.p  computed by mfma_f32_16x16x32_bf16 with split-bf16
//   K-packing:  A_k = [-qhi(3), -qhi(3), -qlo(3), 1, 1, 0...]
//               B_k = [ phi(3),  plo(3),  phi(3), hhi, hlo, 0...]
//   (q.p ~ qhi.phi + qhi.plo + qlo.phi; lo*lo dropped ~2e-5; h = 0.5|p|^2
//    split hi/lo. bf16 products are exact in fp32 -> d2 error ~2e-4.)
// d2 = max(0, 2*s_min + |q|^2) reconstructed per query (min is monotone).
// A/B fragment k-mapping assumption (k = (lane>>4)*8 + elem) is safe even if
// HW differs: we build BOTH operands with the same mapping, so any mismatch
// is a k-permutation applied to both sides -> contraction unchanged.
// C/D layout (col=lane&15, row=(lane>>4)*4+reg) is HW-verified (m89).
//
// Pipeline: prep (pack frag arrays, 16MB ws) -> main (1024 blocks: per-block
// 512 rows x 512-point col-shard, B-frags staged in 32KB LDS, per wave 8
// row-tiles x 32 col-tiles, running min3 over col-tile pairs, cross-lane
// min, partials to ws) -> reduce (min over 4 shards + d2 + sum).
// ~40 us of dur_us is the harness's 268MB ws poison-fill (fixed).

typedef __attribute__((ext_vector_type(8))) short bf16x8;
typedef __attribute__((ext_vector_type(4))) float f32x4;
typedef __attribute__((ext_vector_type(4))) unsigned int u32x4;

constexpr int B_SZ    = 32;
constexpr int NPTS    = 2048;
constexpr int BLOCK   = 256;
constexpr int NQ      = 2 * B_SZ * NPTS;    // 131072 query slots (both dirs)
constexpr int RT      = 8;                  // row-tiles per wave (128 rows)
constexpr int STRIPES = 4;                  // 2048 rows / (4 waves * 8rt * 16)
constexpr int CS      = 4;                  // col shards (512 pts each)
constexpr int CT      = 128 / CS;           // col-tiles per shard = 32

constexpr size_t FRAG_U4_PER_ARR = (size_t)B_SZ * 128 * 64;  // 262144 uint4 = 4MB
constexpr size_t FRAG_BYTES      = 4 * FRAG_U4_PER_ARR * 16; // 16MB (4 arrays)

__device__ __forceinline__ unsigned short f2bf(float f) {   // RNE f32->bf16
    unsigned int u = __float_as_uint(f);
    u += 0x7FFFu + ((u >> 16) & 1u);
    return (unsigned short)(u >> 16);
}
__device__ __forceinline__ float bf2f(unsigned short h) {
    return __uint_as_float(((unsigned int)h) << 16);
}

// Build packed fragment arrays: arr 0:A_x 1:B_x 2:A_y 3:B_y.
// Frag layout (assumed, permutation-safe): lane l -> M/N index = l&15,
// k = (l>>4)*8 + e; reg r packs elems 2r (lo16), 2r+1 (hi16).
__global__ __launch_bounds__(BLOCK)
void prep_frags(const float* __restrict__ x, const float* __restrict__ y,
                u32x4* __restrict__ frags) {
    const int t    = blockIdx.x * BLOCK + threadIdx.x;   // 1,048,576 total
    const int lane = t & 63;
    const int rt   = (t >> 6) & 127;
    const int b    = (t >> 13) & 31;
    const int arr  = t >> 18;
    const float* cloud = (arr >= 2) ? y : x;
    const int form = arr & 1;                 // 0 = A-form, 1 = B-form
    const int pi = b * NPTS + rt * 16 + (lane & 15);
    const float vx = cloud[pi*3+0], vy = cloud[pi*3+1], vz = cloud[pi*3+2];
    const unsigned short hx = f2bf(vx), hy = f2bf(vy), hz = f2bf(vz);
    const unsigned short lx = f2bf(vx - bf2f(hx));
    const unsigned short ly = f2bf(vy - bf2f(hy));
    const unsigned short lz = f2bf(vz - bf2f(hz));
    unsigned short k0,k1,k2,k3,k4,k5,k6,k7,k8,k9,k10;
    if (form == 0) {            // A: [-qhi,-qhi,-qlo, 1, 1]
        k0 = hx ^ 0x8000; k1 = hy ^ 0x8000; k2 = hz ^ 0x8000;
        k3 = k0; k4 = k1; k5 = k2;
        k6 = lx ^ 0x8000; k7 = ly ^ 0x8000; k8 = lz ^ 0x8000;
        k9 = 0x3F80; k10 = 0x3F80;            // bf16 1.0
    } else {                    // B: [phi, plo, phi, hhi, hlo]
        const float h = 0.5f * fmaf(vx, vx, fmaf(vy, vy, vz * vz));
        const unsigned short hh = f2bf(h);
        k0 = hx; k1 = hy; k2 = hz;
        k3 = lx; k4 = ly; k5 = lz;
        k6 = hx; k7 = hy; k8 = hz;
        k9 = hh; k10 = f2bf(h - bf2f(hh));
    }
    const int g = lane >> 4;    // k-group: g0 holds k0-7, g1 k8-15, g2/g3 zero
    unsigned int e01 = 0, e23 = 0, e45 = 0, e67 = 0;
    if (g == 0) {
        e01 = k0 | ((unsigned)k1 << 16);
        e23 = k2 | ((unsigned)k3 << 16);
        e45 = k4 | ((unsigned)k5 << 16);
        e67 = k6 | ((unsigned)k7 << 16);
    } else if (g == 1) {
        e01 = k8 | ((unsigned)k9 << 16);
        e23 = (unsigned)k10;
    }
    u32x4 r = {e01, e23, e45, e67};
    frags[((size_t)(arr * B_SZ + b) * 128 + rt) * 64 + lane] = r;
}

// grid 1024: [dir(2)][b(32)][stripe(4)][cs(4)]; 4 waves; wave = 8 row-tiles.
__global__ __launch_bounds__(BLOCK, 4)
void chamfer_mfma(const u32x4* __restrict__ frags, float* __restrict__ part) {
    __shared__ u32x4 blds[CT * 64];   // 32 KB: this shard's B-fragments
    const int bid    = blockIdx.x;
    const int cs     = bid & (CS - 1);
    const int stripe = (bid >> 2) & (STRIPES - 1);
    const int b      = (bid >> 4) & 31;
    const int dir    = bid >> 9;

    const u32x4* Aarr = frags + (size_t)(dir ? 2 : 0) * FRAG_U4_PER_ARR;
    const u32x4* Barr = frags + (size_t)(dir ? 1 : 3) * FRAG_U4_PER_ARR;

    // Stage B-frags (linear 32KB copy, coalesced uint4).
    const u32x4* bsrc = Barr + ((size_t)b * 128 + cs * CT) * 64;
    #pragma unroll
    for (int i = 0; i < CT * 64 / BLOCK; ++i)
        blds[i * BLOCK + threadIdx.x] = bsrc[i * BLOCK + threadIdx.x];

    const int w = threadIdx.x >> 6, lane = threadIdx.x & 63;
    const int rt0 = stripe * 32 + w * RT;

    bf16x8 afrag[RT];
    #pragma unroll
    for (int r = 0; r < RT; ++r)
        afrag[r] = __builtin_bit_cast(
            bf16x8, Aarr[((size_t)b * 128 + rt0 + r) * 64 + lane]);

    __syncthreads();

    f32x4 rmin[RT];
    #pragma unroll
    for (int r = 0; r < RT; ++r)
        rmin[r] = (f32x4){3e38f, 3e38f, 3e38f, 3e38f};

    for (int ct = 0; ct < CT; ct += 2) {
        const bf16x8 bf0 = __builtin_bit_cast(bf16x8, blds[ct * 64 + lane]);
        const bf16x8 bf1 = __builtin_bit_cast(bf16x8, blds[ct * 64 + 64 + lane]);
        #pragma unroll
        for (int r = 0; r < RT; ++r) {
            const f32x4 z = {0.f, 0.f, 0.f, 0.f};
            f32x4 a0 = __builtin_amdgcn_mfma_f32_16x16x32_bf16(afrag[r], bf0, z, 0, 0, 0);
            f32x4 a1 = __builtin_amdgcn_mfma_f32_16x16x32_bf16(afrag[r], bf1, z, 0, 0, 0);
            #pragma unroll
            for (int j = 0; j < 4; ++j)   // v_min3: two tiles into running min
                rmin[r][j] = fminf(fminf(a0[j], a1[j]), rmin[r][j]);
        }
    }

    // Min across the 16-col dimension: cols live in lanes sharing l>>4.
    #pragma unroll
    for (int r = 0; r < RT; ++r)
        #pragma unroll
        for (int j = 0; j < 4; ++j) {
            float v = rmin[r][j];
            v = fminf(v, __shfl_xor(v, 1, 64));
            v = fminf(v, __shfl_xor(v, 2, 64));
            v = fminf(v, __shfl_xor(v, 4, 64));
            v = fminf(v, __shfl_xor(v, 8, 64));
            rmin[r][j] = v;
        }

    if ((lane & 15) == 0) {   // row = (rt0+r)*16 + g*4 + j  (C/D layout, m89)
        const int g = lane >> 4;
        float* dst = part + (size_t)cs * NQ + (size_t)(dir * B_SZ + b) * NPTS;
        #pragma unroll
        for (int r = 0; r < RT; ++r)
            #pragma unroll
            for (int j = 0; j < 4; ++j)
                dst[(rt0 + r) * 16 + g * 4 + j] = rmin[r][j];
    }
}

// Min over CS shards, reconstruct d2 = max(0, 2*s + |q|^2), sum. 512 blocks.
__global__ __launch_bounds__(BLOCK)
void chamfer_reduce(const float* __restrict__ part,
                    const float* __restrict__ x, const float* __restrict__ y,
                    float* __restrict__ out) {
    __shared__ float wsum[BLOCK / 64];
    const int gq = blockIdx.x * BLOCK + threadIdx.x;
    float m = part[gq];
    #pragma unroll
    for (int s = 1; s < CS; ++s)
        m = fminf(m, part[(size_t)s * NQ + gq]);
    const int dir = gq >> 16;
    const int idx = gq & 65535;             // b*2048 + row
    const float* q = (dir ? y : x) + (size_t)idx * 3;
    const float qx = q[0], qy = q[1], qz = q[2];
    const float q2 = fmaf(qx, qx, fmaf(qy, qy, qz * qz));
    float s = fmaxf(0.0f, fmaf(2.0f, m, q2));
    #pragma unroll
    for (int off = 32; off > 0; off >>= 1) s += __shfl_down(s, off, 64);
    if ((threadIdx.x & 63) == 0) wsum[threadIdx.x >> 6] = s;
    __syncthreads();
    if (threadIdx.x == 0) {
        float tt = (wsum[0] + wsum[1]) + (wsum[2] + wsum[3]);
        atomicAdd(out, tt * (1.0f / B_SZ));
    }
}

// Fallback (tiny ws): proven v4 vector kernel, direct sum. grid 64.
__global__ __launch_bounds__(BLOCK, 4)
void chamfer_fallback(const float* __restrict__ x, const float* __restrict__ y,
                      float* __restrict__ out) {
    __shared__ float4 pts[NPTS];
    __shared__ float wsum[BLOCK / 64];
    const int b = blockIdx.x & 31, dir = blockIdx.x >> 5;
    const float* q = ((dir == 0) ? x : y) + (size_t)b * NPTS * 3;
    const float* p = ((dir == 0) ? y : x) + (size_t)b * NPTS * 3;
    for (int idx = threadIdx.x; idx < NPTS * 3; idx += BLOCK) {
        int pt = idx / 3, c = idx - pt * 3;
        ((float*)&pts[pt])[c] = p[idx];
    }
    __syncthreads();
    for (int pt = threadIdx.x; pt < NPTS; pt += BLOCK) {
        float4 v = pts[pt];
        pts[pt].w = 0.5f * fmaf(v.x, v.x, fmaf(v.y, v.y, v.z * v.z));
    }
    __syncthreads();
    float qx[8], qy[8], qz[8], q2[8], best[8];
    #pragma unroll
    for (int k = 0; k < 8; ++k) {
        int qi = threadIdx.x + k * BLOCK;
        qx[k] = q[qi*3]; qy[k] = q[qi*3+1]; qz[k] = q[qi*3+2];
        q2[k] = fmaf(qx[k], qx[k], fmaf(qy[k], qy[k], qz[k]*qz[k]));
        best[k] = 3.0e38f;
    }
    #pragma unroll 4
    for (int n = 0; n < NPTS; n += 2) {
        float4 pa = pts[n], pc = pts[n+1];
        #pragma unroll
        for (int k = 0; k < 8; ++k) {
            float sa = fmaf(-qx[k], pa.x, fmaf(-qy[k], pa.y, fmaf(-qz[k], pa.z, pa.w)));
            float sb = fmaf(-qx[k], pc.x, fmaf(-qy[k], pc.y, fmaf(-qz[k], pc.z, pc.w)));
            best[k] = fminf(fminf(best[k], sa), sb);
        }
    }
    float s = 0.0f;
    #pragma unroll
    for (int k = 0; k < 8; ++k) s += fmaxf(0.0f, fmaf(2.0f, best[k], q2[k]));
    #pragma unroll
    for (int off = 32; off > 0; off >>= 1) s += __shfl_down(s, off, 64);
    if ((threadIdx.x & 63) == 0) wsum[threadIdx.x >> 6] = s;
    __syncthreads();
    if (threadIdx.x == 0) {
        float tt = 0.f;
        #pragma unroll
        for (int w = 0; w < BLOCK / 64; ++w) tt += wsum[w];
        atomicAdd(out, tt * (1.0f / B_SZ));
    }
}

extern "C" void kernel_launch(void* const* d_in, const int* in_sizes, int n_in,
                              void* d_out, int out_size, void* d_ws, size_t ws_size,
                              hipStream_t stream) {
    const float* x = (const float*)d_in[0];
    const float* y = (const float*)d_in[1];
    float* out = (float*)d_out;

    hipMemsetAsync(out, 0, sizeof(float) * out_size, stream);

    const size_t need = FRAG_BYTES + (size_t)CS * NQ * sizeof(float);  // ~18MB
    if (ws_size >= need) {
        u32x4* frags = (u32x4*)d_ws;
        float* part  = (float*)((char*)d_ws + FRAG_BYTES);
        prep_frags  <<<4096, BLOCK, 0, stream>>>(x, y, frags);
        chamfer_mfma<<<1024, BLOCK, 0, stream>>>(frags, part);
        chamfer_reduce<<<NQ / BLOCK, BLOCK, 0, stream>>>(part, x, y, out);
    } else {
        chamfer_fallback<<<2 * B_SZ, BLOCK, 0, stream>>>(x, y, out);
    }
}

// Round 7
// 74.826 us; speedup vs baseline: 1.2025x; 1.2025x over previous
//
#include <hip/hip_runtime.h>

// Chamfer loss: B=32, N=M=2048, D=3, fp32 in, scalar fp32 out.
// loss = sum_b [ sum_m min_n d2 + sum_n min_m d2 ] / B
//
// v6: single fused MFMA kernel, 32x32x16 shape (K=16 fits the 11-slot
// split-bf16 packing -> 2x useful-K density vs v5's 16x16x32; 1024 scores
// per ~8-cyc MFMA). No prep kernel, no workspace, no reduce kernel.
//
// Score: s[q][p] = h_p - q.p  with split bf16 (q ~ qh+ql, p ~ ph+pl):
//   A_k = [-qhx,-qhy,-qhz, -qhx,-qhy,-qhz, -qlx,-qly | -qlz, 1, 1, 0...]
//   B_k = [ phx, phy, phz,  plx, ply, plz,  phx, phy |  phz, hh, hl, 0...]
//   sum = h - qh.ph - qh.pl - ql.ph   (lo*lo dropped, ~2e-5; h = 0.5|p|^2)
// d2 = max(0, 2*s_min + |q|^2) per query row (min is monotone).
// Both operands are built with the SAME assumed lane->k map, so any HW
// k-permutation cancels (v5 validated this method, absmax=0). C/D layout
// col=lane&31, row=(reg&3)+8*(reg>>2)+4*(lane>>5) is HW-verified (m74/m101).
//
// Grid 512 = [dir(2)][batch(32)][stripe(8)]; 256 thr = 4 waves; RT=2
// row-tiles (64 rows) per wave; block covers 256 query rows x all 2048
// opposing points (B-frags packed in-block to 64KB LDS -> 2 blocks/CU).
// Scan: per 2 col-tiles: 2 ds_read_b128 + 2 MFMA per rt + 16 v_min3.
// Then 5-level shfl_xor col-min (within 32-lane groups), predicated LDS
// row-min write, per-row d2 reconstruction, block sum, one atomicAdd.
// ~44 us of dur_us is the harness's 268MB ws poison-fill (fixed floor).

typedef __attribute__((ext_vector_type(8)))  short bf16x8;
typedef __attribute__((ext_vector_type(16))) float f32x16;
typedef __attribute__((ext_vector_type(4)))  unsigned int u32x4;

constexpr int B_SZ    = 32;
constexpr int NPTS    = 2048;
constexpr int BLOCK   = 256;
constexpr int STRIPES = 8;                 // 2048 rows / 256 rows-per-block
constexpr int RT      = 2;                 // 32-row tiles per wave
constexpr int CT      = NPTS / 32;         // 64 col-tiles

__device__ __forceinline__ unsigned short f2bf(float f) {   // RNE f32->bf16
    unsigned int u = __float_as_uint(f);
    u += 0x7FFFu + ((u >> 16) & 1u);
    return (unsigned short)(u >> 16);
}
__device__ __forceinline__ float bf2f(unsigned short h) {
    return __uint_as_float(((unsigned int)h) << 16);
}
__device__ __forceinline__ unsigned int pk(unsigned short lo, unsigned short hi) {
    return (unsigned int)lo | ((unsigned int)hi << 16);
}

__global__ __launch_bounds__(BLOCK, 2)
void chamfer_fused(const float* __restrict__ x, const float* __restrict__ y,
                   float* __restrict__ out) {
    __shared__ u32x4 blds[CT * 64];        // 64 KB: B-fragments, whole cloud
    __shared__ float rowm[BLOCK];          // per-block-row mins
    __shared__ float wsum[BLOCK / 64];

    const int bid    = blockIdx.x;
    const int stripe = bid & (STRIPES - 1);
    const int b      = (bid >> 3) & 31;
    const int dir    = bid >> 8;

    const float* q = ((dir == 0) ? x : y) + (size_t)b * NPTS * 3;  // queries
    const float* p = ((dir == 0) ? y : x) + (size_t)b * NPTS * 3;  // points

    // ---- Pack B-fragments for the whole opposing cloud into LDS.
    // Tile ct (cols = points ct*32..+31): entry [ct*64 + g*32 + col].
    for (int pi = threadIdx.x; pi < NPTS; pi += BLOCK) {
        const float vx = p[pi * 3 + 0], vy = p[pi * 3 + 1], vz = p[pi * 3 + 2];
        const unsigned short hx = f2bf(vx), hy = f2bf(vy), hz = f2bf(vz);
        const unsigned short lx = f2bf(vx - bf2f(hx));
        const unsigned short ly = f2bf(vy - bf2f(hy));
        const unsigned short lz = f2bf(vz - bf2f(hz));
        const float h = 0.5f * fmaf(vx, vx, fmaf(vy, vy, vz * vz));
        const unsigned short hh = f2bf(h);
        const unsigned short hl = f2bf(h - bf2f(hh));
        const int ct = pi >> 5, col = pi & 31;
        u32x4 g0 = {pk(hx, hy), pk(hz, lx), pk(ly, lz), pk(hx, hy)};
        u32x4 g1 = {pk(hz, hh), pk(hl, 0), 0u, 0u};
        blds[ct * 64 + col]      = g0;     // k0..7
        blds[ct * 64 + 32 + col] = g1;     // k8..15
    }

    // ---- Pack A-fragments (this wave's RT row-tiles) into registers.
    const int w    = threadIdx.x >> 6;
    const int lane = threadIdx.x & 63;
    const int g    = lane >> 5;            // k-half
    const int r32  = lane & 31;            // row within tile
    bf16x8 afrag[RT];
    #pragma unroll
    for (int rt = 0; rt < RT; ++rt) {
        const int row = stripe * 256 + w * (RT * 32) + rt * 32 + r32;
        const float vx = q[row * 3 + 0], vy = q[row * 3 + 1], vz = q[row * 3 + 2];
        const unsigned short hx = f2bf(vx) ^ 0x8000, hy = f2bf(vy) ^ 0x8000,
                             hz = f2bf(vz) ^ 0x8000;
        const unsigned short lx = f2bf(vx - bf2f(hx ^ 0x8000)) ^ 0x8000;
        const unsigned short ly = f2bf(vy - bf2f(hy ^ 0x8000)) ^ 0x8000;
        const unsigned short lz = f2bf(vz - bf2f(hz ^ 0x8000)) ^ 0x8000;
        u32x4 fr;
        if (g == 0)   // k0..7 = [-qhx,-qhy,-qhz,-qhx,-qhy,-qhz,-qlx,-qly]
            fr = (u32x4){pk(hx, hy), pk(hz, hx), pk(hy, hz), pk(lx, ly)};
        else          // k8..15 = [-qlz, 1, 1, 0,0,0,0,0]  (bf16 1.0 = 0x3F80)
            fr = (u32x4){pk(lz, 0x3F80), pk(0x3F80, 0), 0u, 0u};
        afrag[rt] = __builtin_bit_cast(bf16x8, fr);
    }
    __syncthreads();

    // ---- Scan: all 64 col-tiles, running min3 into 16-reg accumulators.
    f32x16 rmin[RT];
    #pragma unroll
    for (int rt = 0; rt < RT; ++rt)
        #pragma unroll
        for (int j = 0; j < 16; ++j) rmin[rt][j] = 3.0e38f;

    for (int ct = 0; ct < CT; ct += 2) {
        const bf16x8 b0 = __builtin_bit_cast(bf16x8, blds[ct * 64 + lane]);
        const bf16x8 b1 = __builtin_bit_cast(bf16x8, blds[ct * 64 + 64 + lane]);
        #pragma unroll
        for (int rt = 0; rt < RT; ++rt) {
            const f32x16 z = {0.f,0.f,0.f,0.f,0.f,0.f,0.f,0.f,
                              0.f,0.f,0.f,0.f,0.f,0.f,0.f,0.f};
            f32x16 a0 = __builtin_amdgcn_mfma_f32_32x32x16_bf16(afrag[rt], b0, z, 0, 0, 0);
            f32x16 a1 = __builtin_amdgcn_mfma_f32_32x32x16_bf16(afrag[rt], b1, z, 0, 0, 0);
            #pragma unroll
            for (int j = 0; j < 16; ++j)   // fuses to v_min3_f32
                rmin[rt][j] = fminf(fminf(a0[j], a1[j]), rmin[rt][j]);
        }
    }

    // ---- Col-min: butterfly over the 32 lanes of each k-half group.
    #pragma unroll
    for (int rt = 0; rt < RT; ++rt)
        #pragma unroll
        for (int j = 0; j < 16; ++j) {
            float v = rmin[rt][j];
            v = fminf(v, __shfl_xor(v, 1, 64));
            v = fminf(v, __shfl_xor(v, 2, 64));
            v = fminf(v, __shfl_xor(v, 4, 64));
            v = fminf(v, __shfl_xor(v, 8, 64));
            v = fminf(v, __shfl_xor(v, 16, 64));
            rmin[rt][j] = v;
        }

    // ---- One writer per row: C/D row = (j&3) + 8*(j>>2) + 4*g.
    #pragma unroll
    for (int rt = 0; rt < RT; ++rt)
        #pragma unroll
        for (int j = 0; j < 16; ++j) {
            const int row = (j & 3) + 8 * (j >> 2) + 4 * g;
            if (r32 == row)
                rowm[w * (RT * 32) + rt * 32 + row] = rmin[rt][j];
        }
    __syncthreads();

    // ---- Reconstruct d2 per row, block-sum, one atomic.
    const int t    = threadIdx.x;
    const int grow = stripe * 256 + t;
    const float qx = q[grow * 3 + 0], qy = q[grow * 3 + 1], qz = q[grow * 3 + 2];
    const float q2 = fmaf(qx, qx, fmaf(qy, qy, qz * qz));
    float s = fmaxf(0.0f, fmaf(2.0f, rowm[t], q2));
    #pragma unroll
    for (int off = 32; off > 0; off >>= 1) s += __shfl_down(s, off, 64);
    if ((t & 63) == 0) wsum[t >> 6] = s;
    __syncthreads();
    if (t == 0) {
        float tt = 0.f;
        #pragma unroll
        for (int wv = 0; wv < BLOCK / 64; ++wv) tt += wsum[wv];
        atomicAdd(out, tt * (1.0f / B_SZ));
    }
}

extern "C" void kernel_launch(void* const* d_in, const int* in_sizes, int n_in,
                              void* d_out, int out_size, void* d_ws, size_t ws_size,
                              hipStream_t stream) {
    const float* x = (const float*)d_in[0];
    const float* y = (const float*)d_in[1];
    float* out = (float*)d_out;

    hipMemsetAsync(out, 0, sizeof(float) * out_size, stream);
    chamfer_fused<<<2 * B_SZ * STRIPES, BLOCK, 0, stream>>>(x, y, out);
}

// Round 8
// 71.230 us; speedup vs baseline: 1.2632x; 1.0505x over previous
//
#include <hip/hip_runtime.h>

// Chamfer loss: B=32, N=M=2048, D=3, fp32 in, scalar fp32 out.
// loss = sum_b [ sum_m min_n d2 + sum_n min_m d2 ] / B
//
// v7 = v6 (single fused 32x32x16 MFMA kernel) with the reduction tail fixed:
//  - v6's 5-level __shfl_xor butterfly (160 dependent ds_bpermute + 160 fmin
//    per wave, serial lgkmcnt chains) + predicated row-writes + rowm round
//    trip are replaced by an LDS transpose-reduce aliased onto the dead
//    B-fragment buffer: 32 conflict-free ds_write_b32 + 32 conflict-free
//    ds_read_b32 per thread (all independent), then a 31-op fmin tree.
//  - zero-C hoisted, ct-loop unrolled x2 (8 MFMAs in flight).
//
// Score math (validated absmax=0 in v5/v6): s[q][p] = h_p - q.p, split bf16:
//   A_k = [-qhx,-qhy,-qhz, -qhx,-qhy,-qhz, -qlx,-qly | -qlz, 1, 1, 0...]
//   B_k = [ phx, phy, phz,  plx, ply, plz,  phx, phy |  phz, hh, hl, 0...]
// d2 = max(0, 2*s_min + |q|^2) per row (min is monotone). Both operands use
// the same assumed lane->k map, so any HW k-permutation cancels. C/D layout
// col=lane&31, row=(reg&3)+8*(reg>>2)+4*(lane>>5) is HW-verified (m74/m101).
//
// Grid 512 = [dir(2)][batch(32)][stripe(8)]; 4 waves; RT=2 row-tiles/wave;
// block = 256 query rows x all 2048 opposing points (B-frags in 64KB LDS,
// 2 blocks/CU). ~48-50 us of dur_us is harness floor (256MB ws poison fill
// + d_in restore + gaps) — untouchable.

typedef __attribute__((ext_vector_type(8)))  short bf16x8;
typedef __attribute__((ext_vector_type(16))) float f32x16;
typedef __attribute__((ext_vector_type(4)))  unsigned int u32x4;

constexpr int B_SZ    = 32;
constexpr int NPTS    = 2048;
constexpr int BLOCK   = 256;
constexpr int STRIPES = 8;                 // 2048 rows / 256 rows-per-block
constexpr int RT      = 2;                 // 32-row tiles per wave
constexpr int CT      = NPTS / 32;         // 64 col-tiles
constexpr int CSTRIDE = 33;                // colm row stride (conflict-free)

__device__ __forceinline__ unsigned short f2bf(float f) {   // RNE f32->bf16
    unsigned int u = __float_as_uint(f);
    u += 0x7FFFu + ((u >> 16) & 1u);
    return (unsigned short)(u >> 16);
}
__device__ __forceinline__ float bf2f(unsigned short h) {
    return __uint_as_float(((unsigned int)h) << 16);
}
__device__ __forceinline__ unsigned int pk(unsigned short lo, unsigned short hi) {
    return (unsigned int)lo | ((unsigned int)hi << 16);
}

__global__ __launch_bounds__(BLOCK, 2)
void chamfer_fused(const float* __restrict__ x, const float* __restrict__ y,
                   float* __restrict__ out) {
    __shared__ u32x4 blds[CT * 64];        // 64 KB: B-frags; reused as colm
    __shared__ float wsum[BLOCK / 64];

    const int bid    = blockIdx.x;
    const int stripe = bid & (STRIPES - 1);
    const int b      = (bid >> 3) & 31;
    const int dir    = bid >> 8;

    const float* q = ((dir == 0) ? x : y) + (size_t)b * NPTS * 3;  // queries
    const float* p = ((dir == 0) ? y : x) + (size_t)b * NPTS * 3;  // points

    // ---- Pack B-fragments for the whole opposing cloud into LDS.
    for (int pi = threadIdx.x; pi < NPTS; pi += BLOCK) {
        const float vx = p[pi * 3 + 0], vy = p[pi * 3 + 1], vz = p[pi * 3 + 2];
        const unsigned short hx = f2bf(vx), hy = f2bf(vy), hz = f2bf(vz);
        const unsigned short lx = f2bf(vx - bf2f(hx));
        const unsigned short ly = f2bf(vy - bf2f(hy));
        const unsigned short lz = f2bf(vz - bf2f(hz));
        const float h = 0.5f * fmaf(vx, vx, fmaf(vy, vy, vz * vz));
        const unsigned short hh = f2bf(h);
        const unsigned short hl = f2bf(h - bf2f(hh));
        const int ct = pi >> 5, col = pi & 31;
        u32x4 g0 = {pk(hx, hy), pk(hz, lx), pk(ly, lz), pk(hx, hy)};
        u32x4 g1 = {pk(hz, hh), pk(hl, 0), 0u, 0u};
        blds[ct * 64 + col]      = g0;     // k0..7
        blds[ct * 64 + 32 + col] = g1;     // k8..15
    }

    // ---- Pack A-fragments (this wave's RT row-tiles) into registers.
    const int w    = threadIdx.x >> 6;
    const int lane = threadIdx.x & 63;
    const int g    = lane >> 5;            // k-half
    const int r32  = lane & 31;            // row within tile
    bf16x8 afrag[RT];
    #pragma unroll
    for (int rt = 0; rt < RT; ++rt) {
        const int row = stripe * 256 + w * (RT * 32) + rt * 32 + r32;
        const float vx = q[row * 3 + 0], vy = q[row * 3 + 1], vz = q[row * 3 + 2];
        const unsigned short hx = f2bf(vx) ^ 0x8000, hy = f2bf(vy) ^ 0x8000,
                             hz = f2bf(vz) ^ 0x8000;
        const unsigned short lx = f2bf(vx - bf2f(hx ^ 0x8000)) ^ 0x8000;
        const unsigned short ly = f2bf(vy - bf2f(hy ^ 0x8000)) ^ 0x8000;
        const unsigned short lz = f2bf(vz - bf2f(hz ^ 0x8000)) ^ 0x8000;
        u32x4 fr;
        if (g == 0)
            fr = (u32x4){pk(hx, hy), pk(hz, hx), pk(hy, hz), pk(lx, ly)};
        else
            fr = (u32x4){pk(lz, 0x3F80), pk(0x3F80, 0), 0u, 0u};
        afrag[rt] = __builtin_bit_cast(bf16x8, fr);
    }
    __syncthreads();

    // ---- Scan all 64 col-tiles; running min3 into 16-reg accumulators.
    const f32x16 z = {0.f,0.f,0.f,0.f,0.f,0.f,0.f,0.f,
                      0.f,0.f,0.f,0.f,0.f,0.f,0.f,0.f};
    f32x16 rmin[RT];
    #pragma unroll
    for (int rt = 0; rt < RT; ++rt)
        #pragma unroll
        for (int j = 0; j < 16; ++j) rmin[rt][j] = 3.0e38f;

    #pragma unroll 2
    for (int ct = 0; ct < CT; ct += 2) {
        const bf16x8 b0 = __builtin_bit_cast(bf16x8, blds[ct * 64 + lane]);
        const bf16x8 b1 = __builtin_bit_cast(bf16x8, blds[ct * 64 + 64 + lane]);
        #pragma unroll
        for (int rt = 0; rt < RT; ++rt) {
            f32x16 a0 = __builtin_amdgcn_mfma_f32_32x32x16_bf16(afrag[rt], b0, z, 0, 0, 0);
            f32x16 a1 = __builtin_amdgcn_mfma_f32_32x32x16_bf16(afrag[rt], b1, z, 0, 0, 0);
            #pragma unroll
            for (int j = 0; j < 16; ++j)   // v_min3_f32
                rmin[rt][j] = fminf(fminf(a0[j], a1[j]), rmin[rt][j]);
        }
    }

    // ---- Transpose-reduce: write col-partials to LDS (aliased over blds),
    // conflict-free (banks (row+c)%32 on write, (row+k)%32 on read).
    __syncthreads();                        // all B-frag reads done
    float* colm = (float*)blds;             // 256 x 33 floats = 33.8 KB
    #pragma unroll
    for (int rt = 0; rt < RT; ++rt)
        #pragma unroll
        for (int j = 0; j < 16; ++j) {
            const int row = w * (RT * 32) + rt * 32 + (j & 3) + 8 * (j >> 2) + 4 * g;
            colm[row * CSTRIDE + r32] = rmin[rt][j];
        }
    __syncthreads();

    // ---- Thread t owns block-row t: min over 32 col-partials (fmin tree).
    const int t = threadIdx.x;
    float v[32];
    #pragma unroll
    for (int k = 0; k < 32; ++k) v[k] = colm[t * CSTRIDE + k];
    #pragma unroll
    for (int s = 16; s > 0; s >>= 1)
        #pragma unroll
        for (int i = 0; i < s; ++i) v[i] = fminf(v[i], v[i + s]);

    // ---- Reconstruct d2, block-sum, one atomic.
    const int grow = stripe * 256 + t;
    const float qx = q[grow * 3 + 0], qy = q[grow * 3 + 1], qz = q[grow * 3 + 2];
    const float q2 = fmaf(qx, qx, fmaf(qy, qy, qz * qz));
    float s = fmaxf(0.0f, fmaf(2.0f, v[0], q2));
    #pragma unroll
    for (int off = 32; off > 0; off >>= 1) s += __shfl_down(s, off, 64);
    if ((t & 63) == 0) wsum[t >> 6] = s;
    __syncthreads();
    if (t == 0) {
        float tt = 0.f;
        #pragma unroll
        for (int wv = 0; wv < BLOCK / 64; ++wv) tt += wsum[wv];
        atomicAdd(out, tt * (1.0f / B_SZ));
    }
}

extern "C" void kernel_launch(void* const* d_in, const int* in_sizes, int n_in,
                              void* d_out, int out_size, void* d_ws, size_t ws_size,
                              hipStream_t stream) {
    const float* x = (const float*)d_in[0];
    const float* y = (const float*)d_in[1];
    float* out = (float*)d_out;

    hipMemsetAsync(out, 0, sizeof(float) * out_size, stream);
    chamfer_fused<<<2 * B_SZ * STRIPES, BLOCK, 0, stream>>>(x, y, out);
}

// Round 9
// 70.038 us; speedup vs baseline: 1.2847x; 1.0170x over previous
//
#include <hip/hip_runtime.h>

// Chamfer loss: B=32, N=M=2048, D=3, fp32 in, scalar fp32 out.
// loss = sum_b [ sum_m min_n d2 + sum_n min_m d2 ] / B
//
// v8 = v7 with occupancy doubled: the scan was MFMA-latency-bound at 2
// waves/SIMD (kernel ~23 us vs 3.4 us pipe model; v6->v7's small delta
// showed wall ~ per-wave serial cycles). BLOCK=512 (8 waves), RT=1/wave,
// VGPR <= 128 via __launch_bounds__(512,4) -> 2 blocks/CU = 16 waves/CU
// = 4 waves/SIMD. s_setprio(1) around MFMAs (barrier-free scan = the
// regime where it measured +4-7%).
//
// Score math (validated absmax=0 in v5/v6/v7): s[q][p] = h_p - q.p via
// 32x32x16 bf16 MFMA, split bf16:
//   A_k = [-qhx,-qhy,-qhz, -qhx,-qhy,-qhz, -qlx,-qly | -qlz, 1, 1, 0...]
//   B_k = [ phx, phy, phz,  plx, ply, plz,  phx, phy |  phz, hh, hl, 0...]
// d2 = max(0, 2*s_min + |q|^2) per row (min is monotone). Both operands
// use the same assumed lane->k map -> any HW k-permutation cancels. C/D:
// col=lane&31, row=(reg&3)+8*(reg>>2)+4*(lane>>5), HW-verified (m74/m101).
//
// Grid 512 = [dir(2)][batch(32)][stripe(8)]; 8 waves x 32 rows = 256 query
// rows/block x all 2048 opposing points (B-frags in 64KB LDS). Reduction
// tail: XOR-rotate-swizzled 256x32 colm aliased onto the dead B-frag
// buffer (write 2-way/read 2-way bank aliasing = free), 31-op fmin tree,
// d2 reconstruction, block sum, one atomicAdd.
// ~48 us of dur_us is harness floor (256MB ws poison fill + restore +
// gaps) — untouchable.

typedef __attribute__((ext_vector_type(8)))  short bf16x8;
typedef __attribute__((ext_vector_type(16))) float f32x16;
typedef __attribute__((ext_vector_type(4)))  unsigned int u32x4;

constexpr int B_SZ    = 32;
constexpr int NPTS    = 2048;
constexpr int BLOCK   = 512;               // 8 waves
constexpr int STRIPES = 8;                 // 2048 rows / 256 rows-per-block
constexpr int CT      = NPTS / 32;         // 64 col-tiles

__device__ __forceinline__ unsigned short f2bf(float f) {   // RNE f32->bf16
    unsigned int u = __float_as_uint(f);
    u += 0x7FFFu + ((u >> 16) & 1u);
    return (unsigned short)(u >> 16);
}
__device__ __forceinline__ float bf2f(unsigned short h) {
    return __uint_as_float(((unsigned int)h) << 16);
}
__device__ __forceinline__ unsigned int pk(unsigned short lo, unsigned short hi) {
    return (unsigned int)lo | ((unsigned int)hi << 16);
}

__global__ __launch_bounds__(BLOCK, 4)     // cap VGPR at 128 -> 4 waves/SIMD
void chamfer_fused(const float* __restrict__ x, const float* __restrict__ y,
                   float* __restrict__ out) {
    __shared__ u32x4 blds[CT * 64];        // 64 KB B-frags; aliased as colm
    __shared__ float wsum[BLOCK / 64];

    const int bid    = blockIdx.x;
    const int stripe = bid & (STRIPES - 1);
    const int b      = (bid >> 3) & 31;
    const int dir    = bid >> 8;

    const float* q = ((dir == 0) ? x : y) + (size_t)b * NPTS * 3;  // queries
    const float* p = ((dir == 0) ? y : x) + (size_t)b * NPTS * 3;  // points

    // ---- Pack B-fragments for the whole opposing cloud into LDS (4 iters).
    for (int pi = threadIdx.x; pi < NPTS; pi += BLOCK) {
        const float vx = p[pi * 3 + 0], vy = p[pi * 3 + 1], vz = p[pi * 3 + 2];
        const unsigned short hx = f2bf(vx), hy = f2bf(vy), hz = f2bf(vz);
        const unsigned short lx = f2bf(vx - bf2f(hx));
        const unsigned short ly = f2bf(vy - bf2f(hy));
        const unsigned short lz = f2bf(vz - bf2f(hz));
        const float h = 0.5f * fmaf(vx, vx, fmaf(vy, vy, vz * vz));
        const unsigned short hh = f2bf(h);
        const unsigned short hl = f2bf(h - bf2f(hh));
        const int ct = pi >> 5, col = pi & 31;
        u32x4 g0 = {pk(hx, hy), pk(hz, lx), pk(ly, lz), pk(hx, hy)};
        u32x4 g1 = {pk(hz, hh), pk(hl, 0), 0u, 0u};
        blds[ct * 64 + col]      = g0;     // k0..7
        blds[ct * 64 + 32 + col] = g1;     // k8..15
    }

    // ---- Pack this wave's A-fragment (1 row-tile = 32 rows per wave).
    const int w    = threadIdx.x >> 6;     // wave 0..7
    const int lane = threadIdx.x & 63;
    const int g    = lane >> 5;            // k-half
    const int r32  = lane & 31;            // row (A) / col (C) within tile
    const int row  = stripe * 256 + w * 32 + r32;
    bf16x8 afrag;
    {
        const float vx = q[row * 3 + 0], vy = q[row * 3 + 1], vz = q[row * 3 + 2];
        const unsigned short hx = f2bf(vx) ^ 0x8000, hy = f2bf(vy) ^ 0x8000,
                             hz = f2bf(vz) ^ 0x8000;
        const unsigned short lx = f2bf(vx - bf2f(hx ^ 0x8000)) ^ 0x8000;
        const unsigned short ly = f2bf(vy - bf2f(hy ^ 0x8000)) ^ 0x8000;
        const unsigned short lz = f2bf(vz - bf2f(hz ^ 0x8000)) ^ 0x8000;
        u32x4 fr;
        if (g == 0)
            fr = (u32x4){pk(hx, hy), pk(hz, hx), pk(hy, hz), pk(lx, ly)};
        else
            fr = (u32x4){pk(lz, 0x3F80), pk(0x3F80, 0), 0u, 0u};
        afrag = __builtin_bit_cast(bf16x8, fr);
    }
    __syncthreads();

    // ---- Scan all 64 col-tiles; running min3 into 16-reg accumulator.
    const f32x16 z = {0.f,0.f,0.f,0.f,0.f,0.f,0.f,0.f,
                      0.f,0.f,0.f,0.f,0.f,0.f,0.f,0.f};
    f32x16 rmin;
    #pragma unroll
    for (int j = 0; j < 16; ++j) rmin[j] = 3.0e38f;

    #pragma unroll 2
    for (int ct = 0; ct < CT; ct += 2) {
        const bf16x8 b0 = __builtin_bit_cast(bf16x8, blds[ct * 64 + lane]);
        const bf16x8 b1 = __builtin_bit_cast(bf16x8, blds[ct * 64 + 64 + lane]);
        __builtin_amdgcn_s_setprio(1);
        f32x16 a0 = __builtin_amdgcn_mfma_f32_32x32x16_bf16(afrag, b0, z, 0, 0, 0);
        f32x16 a1 = __builtin_amdgcn_mfma_f32_32x32x16_bf16(afrag, b1, z, 0, 0, 0);
        __builtin_amdgcn_s_setprio(0);
        #pragma unroll
        for (int j = 0; j < 16; ++j)       // v_min3_f32
            rmin[j] = fminf(fminf(a0[j], a1[j]), rmin[j]);
    }

    // ---- Transpose-reduce over cols. colm = 256 rows x 32 cols aliased on
    // blds, XOR-rotate swizzle col' = (col+row)&31: write banks (r32+row)&31
    // (2-way across g-halves), read banks (k+lane)&31 (2-way) — both free.
    __syncthreads();                        // all B-frag reads done
    float* colm = (float*)blds;
    #pragma unroll
    for (int j = 0; j < 16; ++j) {
        const int lr = w * 32 + (j & 3) + 8 * (j >> 2) + 4 * g;  // local row
        colm[lr * 32 + ((r32 + lr) & 31)] = rmin[j];
    }
    __syncthreads();

    // ---- Threads 0..255: min over 32 col-partials (fmin tree) + d2.
    const int t = threadIdx.x;
    float s = 0.0f;
    if (t < 256) {
        float v[32];
        #pragma unroll
        for (int k = 0; k < 32; ++k) v[k] = colm[t * 32 + ((k + t) & 31)];
        #pragma unroll
        for (int st = 16; st > 0; st >>= 1)
            #pragma unroll
            for (int i = 0; i < st; ++i) v[i] = fminf(v[i], v[i + st]);
        const int grow = stripe * 256 + t;
        const float qx = q[grow * 3 + 0], qy = q[grow * 3 + 1], qz = q[grow * 3 + 2];
        const float q2 = fmaf(qx, qx, fmaf(qy, qy, qz * qz));
        s = fmaxf(0.0f, fmaf(2.0f, v[0], q2));
    }

    // ---- Block sum, one atomic.
    #pragma unroll
    for (int off = 32; off > 0; off >>= 1) s += __shfl_down(s, off, 64);
    if ((t & 63) == 0) wsum[t >> 6] = s;
    __syncthreads();
    if (t == 0) {
        float tt = 0.f;
        #pragma unroll
        for (int wv = 0; wv < BLOCK / 64; ++wv) tt += wsum[wv];
        atomicAdd(out, tt * (1.0f / B_SZ));
    }
}

extern "C" void kernel_launch(void* const* d_in, const int* in_sizes, int n_in,
                              void* d_out, int out_size, void* d_ws, size_t ws_size,
                              hipStream_t stream) {
    const float* x = (const float*)d_in[0];
    const float* y = (const float*)d_in[1];
    float* out = (float*)d_out;

    hipMemsetAsync(out, 0, sizeof(float) * out_size, stream);
    chamfer_fused<<<2 * B_SZ * STRIPES, BLOCK, 0, stream>>>(x, y, out);
}